// Round 1
// 1606.849 us; speedup vs baseline: 1.0740x; 1.0740x over previous
//
#include <hip/hip_runtime.h>
#include <hip/hip_bf16.h>

// Problem dims (fixed by setup_inputs)
#define B_ROWS 2048
#define K_DIM  3072     // T*d_in = 4*768
#define N_DIM  16384    // d_sae
#define TOPK   128
#define XHAT_ELEMS (B_ROWS * K_DIM)   // 6291456

typedef __bf16 bf16x8 __attribute__((ext_vector_type(8)));
typedef float  f32x4  __attribute__((ext_vector_type(4)));

#define LDSTRIDE 40   // (fallback kernel) ushorts per LDS row

// bf16 round-to-nearest-even, returned as fp32 bit pattern with low 16 zeroed.
__device__ __forceinline__ unsigned bf16rne(float f) {
    unsigned u = __float_as_uint(f);
    unsigned r = u + 0x7fffu + ((u >> 16) & 1u);
    return r & 0xffff0000u;
}
// pack bf16(x) into low 16, bf16(y) into high 16
__device__ __forceinline__ unsigned pk2_rne(float x, float y) {
    return (bf16rne(x) >> 16) | bf16rne(y);
}
__device__ __forceinline__ float lo16f(unsigned u) { return __uint_as_float(u << 16); }
__device__ __forceinline__ float hi16f(unsigned u) { return __uint_as_float(u & 0xffff0000u); }

// 2-bit row-dependent chunk swizzle: spreads 16B ds_read_b128 chunks so each
// 16-lane fragment read is <=2-way on the 32 banks (2-way is free, m136).
__device__ __forceinline__ int swz4(int r) { return (r ^ (r >> 2)) & 3; }

// async global->LDS, 16B per lane (dest must be linear: base + lane*16)
__device__ __forceinline__ void gl_lds16(const void* g, void* l) {
    __builtin_amdgcn_global_load_lds((__attribute__((address_space(1))) const void*)g,
                                     (__attribute__((address_space(3))) void*)l, 16, 0, 0);
}

// ---------------------------------------------------------------------------
// Pre-pass 1: split X (f32 [M][K]) -> Xh, Xl (bf16 [M][K]). 8 elems/thread.
// ---------------------------------------------------------------------------
__global__ __launch_bounds__(256) void split_x_kernel(const float* __restrict__ X,
                                                      unsigned short* __restrict__ Xh,
                                                      unsigned short* __restrict__ Xl) {
    size_t i = ((size_t)blockIdx.x * 256 + threadIdx.x) * 8;
    float4 a = *(const float4*)(X + i);
    float4 b = *(const float4*)(X + i + 4);
    unsigned h0 = pk2_rne(a.x, a.y), h1 = pk2_rne(a.z, a.w);
    unsigned h2 = pk2_rne(b.x, b.y), h3 = pk2_rne(b.z, b.w);
    unsigned l0 = pk2_rne(a.x - lo16f(h0), a.y - hi16f(h0));
    unsigned l1 = pk2_rne(a.z - lo16f(h1), a.w - hi16f(h1));
    unsigned l2 = pk2_rne(b.x - lo16f(h2), b.y - hi16f(h2));
    unsigned l3 = pk2_rne(b.z - lo16f(h3), b.w - hi16f(h3));
    uint4 hv; hv.x = h0; hv.y = h1; hv.z = h2; hv.w = h3;
    uint4 lv; lv.x = l0; lv.y = l1; lv.z = l2; lv.w = l3;
    *(uint4*)(Xh + i) = hv;
    *(uint4*)(Xl + i) = lv;
}

// ---------------------------------------------------------------------------
// Pre-pass 2: split + transpose W (f32 [K][N]) -> WhT, WlT (bf16 [N][K]).
// 64x64 tiles via LDS (stride-65 pad: all accesses <=2-way).
// ---------------------------------------------------------------------------
__global__ __launch_bounds__(256) void split_wT_kernel(const float* __restrict__ W,
                                                       unsigned short* __restrict__ WhT,
                                                       unsigned short* __restrict__ WlT) {
    __shared__ float s[64][65];
    const int t  = threadIdx.x;
    const int k0 = blockIdx.x * 64;   // 48 tiles along K
    const int n0 = blockIdx.y * 64;   // 256 tiles along N
    const int c4 = t & 15, r = t >> 4;

#pragma unroll
    for (int p = 0; p < 4; ++p) {
        int rr = r + p * 16;          // k-local row
        float4 v = *(const float4*)(W + (size_t)(k0 + rr) * N_DIM + n0 + c4 * 4);
        s[rr][c4 * 4 + 0] = v.x;
        s[rr][c4 * 4 + 1] = v.y;
        s[rr][c4 * 4 + 2] = v.z;
        s[rr][c4 * 4 + 3] = v.w;
    }
    __syncthreads();
#pragma unroll
    for (int p = 0; p < 4; ++p) {
        int rr = r + p * 16;          // n-local row of the transposed output
        float v0 = s[c4 * 4 + 0][rr];
        float v1 = s[c4 * 4 + 1][rr];
        float v2 = s[c4 * 4 + 2][rr];
        float v3 = s[c4 * 4 + 3][rr];
        unsigned h01 = pk2_rne(v0, v1), h23 = pk2_rne(v2, v3);
        unsigned l01 = pk2_rne(v0 - lo16f(h01), v1 - hi16f(h01));
        unsigned l23 = pk2_rne(v2 - lo16f(h23), v3 - hi16f(h23));
        size_t o = (size_t)(n0 + rr) * K_DIM + k0 + c4 * 4;
        uint2 hv; hv.x = h01; hv.y = h23;
        uint2 lv; lv.x = l01; lv.y = l23;
        *(uint2*)(WhT + o) = hv;
        *(uint2*)(WlT + o) = lv;
    }
}

// ---------------------------------------------------------------------------
// Encoder GEMM on pre-split bf16 planes. m97 structure: 128x128 tile, BK=32,
// 4 waves (64x64 each), global_load_lds staging (zero VALU conversion),
// 48 MFMA / k-step (3 split products). Chunk-swizzled LDS (source + read).
// ---------------------------------------------------------------------------
__global__ __launch_bounds__(256) void enc_gemm_presplit(
        const unsigned short* __restrict__ Xh, const unsigned short* __restrict__ Xl,
        const unsigned short* __restrict__ WhT, const unsigned short* __restrict__ WlT,
        const float* __restrict__ benc, float* __restrict__ pre) {
    __shared__ unsigned short Ah[128 * 32], Al[128 * 32];
    __shared__ unsigned short Bh[128 * 32], Bl[128 * 32];

    const int t   = threadIdx.x;
    const int bid = blockIdx.x;
    const int mt  = bid & 15;          // M fast-varying: consecutive blocks share W strip
    const int nt  = bid >> 4;
    const int m0  = mt * 128, n0 = nt * 128;

    // Staging: thread t owns LDS 16B slots t and t+256 (rows sr and sr+64).
    // Source chunk is pre-swizzled so LDS slot (row,f) holds data chunk f^swz4(row).
    const int sr = t >> 2;                          // 0..63
    const int sc = ((t & 3) ^ swz4(sr)) * 8;        // swizzled source chunk (elems)
    const size_t rstep = (size_t)64 * K_DIM;

    const unsigned short* xh0 = Xh  + (size_t)(m0 + sr) * K_DIM + sc;
    const unsigned short* xl0 = Xl  + (size_t)(m0 + sr) * K_DIM + sc;
    const unsigned short* wh0 = WhT + (size_t)(n0 + sr) * K_DIM + sc;
    const unsigned short* wl0 = WlT + (size_t)(n0 + sr) * K_DIM + sc;

    unsigned short* ahD0 = &Ah[(size_t)t * 8];
    unsigned short* ahD1 = &Ah[(size_t)(t + 256) * 8];
    unsigned short* alD0 = &Al[(size_t)t * 8];
    unsigned short* alD1 = &Al[(size_t)(t + 256) * 8];
    unsigned short* bhD0 = &Bh[(size_t)t * 8];
    unsigned short* bhD1 = &Bh[(size_t)(t + 256) * 8];
    unsigned short* blD0 = &Bl[(size_t)t * 8];
    unsigned short* blD1 = &Bl[(size_t)(t + 256) * 8];

    f32x4 acc[4][4];
#pragma unroll
    for (int mi = 0; mi < 4; ++mi)
#pragma unroll
        for (int ni = 0; ni < 4; ++ni) acc[mi][ni] = (f32x4)0.f;

    const int w = t >> 6, lane = t & 63;
    const int wm = (w >> 1) * 64, wn = (w & 1) * 64;
    const int fm = lane & 15, fk = lane >> 4;
    const int koff = (fk ^ swz4(fm)) * 8;   // swizzled read chunk (elems)

    for (int k0 = 0; k0 < K_DIM; k0 += 32) {
        __syncthreads();   // previous tile fully consumed
        gl_lds16(xh0 + k0,         ahD0);
        gl_lds16(xh0 + k0 + rstep, ahD1);
        gl_lds16(xl0 + k0,         alD0);
        gl_lds16(xl0 + k0 + rstep, alD1);
        gl_lds16(wh0 + k0,         bhD0);
        gl_lds16(wh0 + k0 + rstep, bhD1);
        gl_lds16(wl0 + k0,         blD0);
        gl_lds16(wl0 + k0 + rstep, blD1);
        __syncthreads();   // vmcnt(0) drain + barrier -> tile visible

        bf16x8 aH[4], aL[4];
#pragma unroll
        for (int mi = 0; mi < 4; ++mi) {
            int r = (wm + mi * 16 + fm) * 32 + koff;
            aH[mi] = *(const bf16x8*)&Ah[r];
            aL[mi] = *(const bf16x8*)&Al[r];
        }
#pragma unroll
        for (int ni = 0; ni < 4; ++ni) {
            int r = (wn + ni * 16 + fm) * 32 + koff;
            bf16x8 bH = *(const bf16x8*)&Bh[r];
            bf16x8 bL = *(const bf16x8*)&Bl[r];
#pragma unroll
            for (int mi = 0; mi < 4; ++mi) {
                acc[mi][ni] = __builtin_amdgcn_mfma_f32_16x16x32_bf16(aH[mi], bH, acc[mi][ni], 0, 0, 0);
                acc[mi][ni] = __builtin_amdgcn_mfma_f32_16x16x32_bf16(aH[mi], bL, acc[mi][ni], 0, 0, 0);
                acc[mi][ni] = __builtin_amdgcn_mfma_f32_16x16x32_bf16(aL[mi], bH, acc[mi][ni], 0, 0, 0);
            }
        }
    }

    // Epilogue: + b_enc, store (C/D layout: col=lane&15, row=(lane>>4)*4+reg)
    const int frow = fk * 4, fcol = fm;
#pragma unroll
    for (int ni = 0; ni < 4; ++ni) {
        int col = n0 + wn + ni * 16 + fcol;
        float bv = benc[col];
#pragma unroll
        for (int mi = 0; mi < 4; ++mi) {
            int row = m0 + wm + mi * 16 + frow;
            float* p = pre + (size_t)row * N_DIM + col;
#pragma unroll
            for (int r = 0; r < 4; ++r) p[(size_t)r * N_DIM] = acc[mi][ni][r] + bv;
        }
    }
}

// ---------------------------------------------------------------------------
// Fallback encoder GEMM (verbatim previous version) — used if ws too small.
// ---------------------------------------------------------------------------
__global__ __launch_bounds__(256) void enc_gemm_mfma(const float* __restrict__ X,
                                                     const float* __restrict__ W,
                                                     const float* __restrict__ benc,
                                                     float* __restrict__ pre) {
    __shared__ unsigned short Ahi[128 * LDSTRIDE], Alo[128 * LDSTRIDE];
    __shared__ unsigned short Bhi[128 * LDSTRIDE], Blo[128 * LDSTRIDE];

    const int t   = threadIdx.x;
    const int bid = blockIdx.x;
    const int mt  = bid & 15;
    const int nt  = bid >> 4;
    const int m0  = mt * 128, n0 = nt * 128;

    int am[4], akq[4], bn[4], bkq[4];
    const float* Xp[4];
    const float* Wp[4];
#pragma unroll
    for (int i = 0; i < 4; ++i) {
        int id = t + 256 * i;
        am[i]  = id >> 3;
        akq[i] = id & 7;
        Xp[i]  = X + (size_t)(m0 + am[i]) * K_DIM + akq[i] * 4;
        bn[i]  = id & 127;
        bkq[i] = id >> 7;
        Wp[i]  = W + (size_t)(bkq[i] * 4) * N_DIM + n0 + bn[i];
    }

    f32x4 acc[4][4];
#pragma unroll
    for (int mi = 0; mi < 4; ++mi)
#pragma unroll
        for (int ni = 0; ni < 4; ++ni) acc[mi][ni] = (f32x4)0.f;

    float4 aR[4];
    float  bR[4][4];
#pragma unroll
    for (int i = 0; i < 4; ++i) {
        aR[i] = *(const float4*)(Xp[i]);
#pragma unroll
        for (int j = 0; j < 4; ++j) bR[i][j] = Wp[i][(size_t)j * N_DIM];
    }

    const int w = t >> 6, lane = t & 63;
    const int wm = (w >> 1) * 64, wn = (w & 1) * 64;
    const int fm = lane & 15, fk = lane >> 4;

    for (int k0 = 0; k0 < K_DIM; k0 += 32) {
        __syncthreads();
#pragma unroll
        for (int i = 0; i < 4; ++i) {
            float4 v = aR[i];
            unsigned h0 = pk2_rne(v.x, v.y), h1 = pk2_rne(v.z, v.w);
            unsigned l0 = pk2_rne(v.x - lo16f(h0), v.y - hi16f(h0));
            unsigned l1 = pk2_rne(v.z - lo16f(h1), v.w - hi16f(h1));
            int off = am[i] * LDSTRIDE + akq[i] * 4;
            uint2 uh; uh.x = h0; uh.y = h1;
            uint2 ul; ul.x = l0; ul.y = l1;
            *(uint2*)&Ahi[off] = uh;
            *(uint2*)&Alo[off] = ul;

            float w0 = bR[i][0], w1 = bR[i][1], w2 = bR[i][2], w3 = bR[i][3];
            unsigned g0 = pk2_rne(w0, w1), g1 = pk2_rne(w2, w3);
            unsigned m0u = pk2_rne(w0 - lo16f(g0), w1 - hi16f(g0));
            unsigned m1u = pk2_rne(w2 - lo16f(g1), w3 - hi16f(g1));
            int boff = bn[i] * LDSTRIDE + bkq[i] * 4;
            uint2 gh; gh.x = g0; gh.y = g1;
            uint2 gl; gl.x = m0u; gl.y = m1u;
            *(uint2*)&Bhi[boff] = gh;
            *(uint2*)&Blo[boff] = gl;
        }
        __syncthreads();

        if (k0 + 32 < K_DIM) {
#pragma unroll
            for (int i = 0; i < 4; ++i) {
                aR[i] = *(const float4*)(Xp[i] + (k0 + 32));
                const float* p = Wp[i] + (size_t)(k0 + 32) * N_DIM;
#pragma unroll
                for (int j = 0; j < 4; ++j) bR[i][j] = p[(size_t)j * N_DIM];
            }
        }

        bf16x8 aH[4], aL[4];
#pragma unroll
        for (int mi = 0; mi < 4; ++mi) {
            int r = (wm + mi * 16 + fm) * LDSTRIDE + fk * 8;
            aH[mi] = *(const bf16x8*)&Ahi[r];
            aL[mi] = *(const bf16x8*)&Alo[r];
        }
#pragma unroll
        for (int ni = 0; ni < 4; ++ni) {
            int r = (wn + ni * 16 + fm) * LDSTRIDE + fk * 8;
            bf16x8 bH = *(const bf16x8*)&Bhi[r];
            bf16x8 bL = *(const bf16x8*)&Blo[r];
#pragma unroll
            for (int mi = 0; mi < 4; ++mi) {
                acc[mi][ni] = __builtin_amdgcn_mfma_f32_16x16x32_bf16(aH[mi], bH, acc[mi][ni], 0, 0, 0);
                acc[mi][ni] = __builtin_amdgcn_mfma_f32_16x16x32_bf16(aH[mi], bL, acc[mi][ni], 0, 0, 0);
                acc[mi][ni] = __builtin_amdgcn_mfma_f32_16x16x32_bf16(aL[mi], bH, acc[mi][ni], 0, 0, 0);
            }
        }
    }

    const int frow = fk * 4, fcol = fm;
#pragma unroll
    for (int ni = 0; ni < 4; ++ni) {
        int col = n0 + wn + ni * 16 + fcol;
        float bv = benc[col];
#pragma unroll
        for (int mi = 0; mi < 4; ++mi) {
            int row = m0 + wm + mi * 16 + frow;
            float* p = pre + (size_t)row * N_DIM + col;
#pragma unroll
            for (int r = 0; r < 4; ++r) p[(size_t)r * N_DIM] = acc[mi][ni][r] + bv;
        }
    }
}

// ---------------------------------------------------------------------------
// Top-k per row (in place). Unchanged.
// ---------------------------------------------------------------------------
__device__ __forceinline__ unsigned sortkey(float f) {
    unsigned u = __float_as_uint(f);
    return (u & 0x80000000u) ? ~u : (u | 0x80000000u);
}

__device__ __forceinline__ int wave_red_int(int v) {
#pragma unroll
    for (int o = 32; o > 0; o >>= 1) v += __shfl_xor(v, o);
    return v;
}

__global__ __launch_bounds__(256) void topk_kernel(float* __restrict__ z,
                                                   int* __restrict__ oIdx,
                                                   float* __restrict__ oVal) {
    __shared__ unsigned short k16[N_DIM];   // 32 KB
    __shared__ int s4[4];
    __shared__ int s_candN;
    __shared__ int s_candIdx[256];
    __shared__ unsigned s_candKey[256];
    __shared__ int s_quota;
    __shared__ int s_outPos;

    const int row = blockIdx.x;
    const int t = threadIdx.x;
    float* zr = z + (size_t)row * N_DIM;

    if (t == 0) { s_candN = 0; s_outPos = 0; }

    for (int i = t; i < N_DIM; i += 256) {
        k16[i] = (unsigned short)(sortkey(zr[i]) >> 16);
    }
    __syncthreads();

    unsigned cur = 0;
    for (int bit = 15; bit >= 0; --bit) {
        unsigned cand = cur | (1u << bit);
        int c = 0;
        for (int i = t; i < N_DIM; i += 256) c += (k16[i] >= cand) ? 1 : 0;
        c = wave_red_int(c);
        __syncthreads();
        if ((t & 63) == 0) s4[t >> 6] = c;
        __syncthreads();
        int total = s4[0] + s4[1] + s4[2] + s4[3];
        if (total >= TOPK) cur = cand;
    }

    {
        int c = 0;
        for (int i = t; i < N_DIM; i += 256) c += (k16[i] > cur) ? 1 : 0;
        c = wave_red_int(c);
        __syncthreads();
        if ((t & 63) == 0) s4[t >> 6] = c;
        __syncthreads();
        int cgt = s4[0] + s4[1] + s4[2] + s4[3];
        if (t == 0) s_quota = TOPK - cgt;
    }
    __syncthreads();

    for (int i = t; i < N_DIM; i += 256) {
        if (k16[i] == (unsigned short)cur) {
            int p = atomicAdd(&s_candN, 1);
            if (p < 256) {
                s_candIdx[p] = i;
                s_candKey[p] = sortkey(zr[i]);
            }
        }
    }
    __syncthreads();

    if (t == 0) {
        int n = s_candN < 256 ? s_candN : 256;
        int q = s_quota;
        if (q > n) q = n;
        s_quota = q;
        for (int a = 0; a < q; ++a) {
            int best = a;
            for (int b = a + 1; b < n; ++b) {
                if (s_candKey[b] > s_candKey[best] ||
                    (s_candKey[b] == s_candKey[best] && s_candIdx[b] < s_candIdx[best]))
                    best = b;
            }
            if (best != a) {
                unsigned tk = s_candKey[a]; s_candKey[a] = s_candKey[best]; s_candKey[best] = tk;
                int ti = s_candIdx[a]; s_candIdx[a] = s_candIdx[best]; s_candIdx[best] = ti;
            }
        }
    }
    __syncthreads();

    const int quota = s_quota;
    for (int i = t; i < N_DIM; i += 256) {
        float f = zr[i];
        unsigned short kk = k16[i];
        bool sel = kk > (unsigned short)cur;
        if (!sel && kk == (unsigned short)cur) {
            for (int j = 0; j < quota; ++j)
                if (s_candIdx[j] == i) { sel = true; break; }
        }
        float zv = sel ? fmaxf(f, 0.f) : 0.f;
        zr[i] = zv;
        if (sel) {
            int p = atomicAdd(&s_outPos, 1);
            oIdx[row * TOPK + p] = i;
            oVal[row * TOPK + p] = zv;
        }
    }
}

// ---------------------------------------------------------------------------
// Sparse decode + fused loss. Unchanged.
// ---------------------------------------------------------------------------
__global__ __launch_bounds__(256) void decode_kernel(const int* __restrict__ idxL,
                                                     const float* __restrict__ valL,
                                                     const float* __restrict__ Wdec,
                                                     const float* __restrict__ bdec,
                                                     const float* __restrict__ x,
                                                     float* __restrict__ xhat,
                                                     float* __restrict__ loss) {
    __shared__ int s_idx[TOPK];
    __shared__ float s_val[TOPK];
    __shared__ float sred[4];

    const int row = blockIdx.x;
    const int t = threadIdx.x;

    if (t < TOPK) {
        s_idx[t] = idxL[row * TOPK + t];
        s_val[t] = valL[row * TOPK + t];
    }
    __syncthreads();

    float acc[12];
#pragma unroll
    for (int e = 0; e < 12; ++e) acc[e] = bdec[t + e * 256];

    for (int i = 0; i < TOPK; ++i) {
        const float v = s_val[i];
        const float* wr = Wdec + (size_t)s_idx[i] * K_DIM;
#pragma unroll
        for (int e = 0; e < 12; ++e)
            acc[e] = fmaf(v, wr[t + e * 256], acc[e]);
    }

    const float* xr = x + (size_t)row * K_DIM;
    float* xo = xhat + (size_t)row * K_DIM;
    float part = 0.f;
#pragma unroll
    for (int e = 0; e < 12; ++e) {
        float d = acc[e] - xr[t + e * 256];
        part = fmaf(d, d, part);
        xo[t + e * 256] = acc[e];
    }

#pragma unroll
    for (int o = 32; o > 0; o >>= 1) part += __shfl_xor(part, o);
    if ((t & 63) == 0) sred[t >> 6] = part;
    __syncthreads();
    if (t == 0) {
        float total = sred[0] + sred[1] + sred[2] + sred[3];
        atomicAdd(loss, total * (1.0f / 8192.0f));
    }
}

// ---------------------------------------------------------------------------
extern "C" void kernel_launch(void* const* d_in, const int* in_sizes, int n_in,
                              void* d_out, int out_size, void* d_ws, size_t ws_size,
                              hipStream_t stream) {
    const float* x     = (const float*)d_in[0];
    const float* W_enc = (const float*)d_in[1];
    const float* b_enc = (const float*)d_in[2];
    const float* W_dec = (const float*)d_in[3];
    const float* b_dec = (const float*)d_in[4];

    float* out  = (float*)d_out;
    float* loss = out;
    float* xhat = out + 1;
    float* z    = out + 1 + XHAT_ELEMS;   // z section doubles as `pre` scratch

    const size_t idxB   = (size_t)B_ROWS * TOPK * sizeof(int);   // 1 MB
    const size_t planeW = (size_t)K_DIM * N_DIM * 2;             // 100.7 MB
    const size_t planeX = (size_t)B_ROWS * K_DIM * 2;            // 12.6 MB
    const size_t need   = 2 * idxB + 2 * planeW + 2 * planeX;    // ~228.6 MB

    int*   oIdx = (int*)d_ws;
    float* oVal = (float*)((char*)d_ws + idxB);

    (void)hipMemsetAsync(loss, 0, sizeof(float), stream);

    if (ws_size >= need) {
        unsigned short* WhT = (unsigned short*)((char*)d_ws + 2 * idxB);
        unsigned short* WlT = (unsigned short*)((char*)WhT + planeW);
        unsigned short* Xh  = (unsigned short*)((char*)WlT + planeW);
        unsigned short* Xl  = (unsigned short*)((char*)Xh + planeX);

        split_x_kernel<<<(B_ROWS * K_DIM) / (8 * 256), 256, 0, stream>>>(x, Xh, Xl);
        split_wT_kernel<<<dim3(K_DIM / 64, N_DIM / 64), 256, 0, stream>>>(W_enc, WhT, WlT);
        enc_gemm_presplit<<<2048, 256, 0, stream>>>(Xh, Xl, WhT, WlT, b_enc, z);
    } else {
        enc_gemm_mfma<<<2048, 256, 0, stream>>>(x, W_enc, b_enc, z);
    }

    topk_kernel<<<B_ROWS, 256, 0, stream>>>(z, oIdx, oVal);

    decode_kernel<<<B_ROWS, 256, 0, stream>>>(oIdx, oVal, W_dec, b_dec, x, xhat, loss);
}

// Round 2
// 1566.517 us; speedup vs baseline: 1.1017x; 1.0257x over previous
//
#include <hip/hip_runtime.h>
#include <hip/hip_bf16.h>

// Problem dims (fixed by setup_inputs)
#define B_ROWS 2048
#define K_DIM  3072     // T*d_in = 4*768
#define N_DIM  16384    // d_sae
#define TOPK   128
#define XHAT_ELEMS (B_ROWS * K_DIM)   // 6291456

typedef __bf16 bf16x8 __attribute__((ext_vector_type(8)));
typedef float  f32x4  __attribute__((ext_vector_type(4)));

#define LDSTRIDE 40   // (fallback kernel) ushorts per LDS row

// bf16 round-to-nearest-even, returned as fp32 bit pattern with low 16 zeroed.
__device__ __forceinline__ unsigned bf16rne(float f) {
    unsigned u = __float_as_uint(f);
    unsigned r = u + 0x7fffu + ((u >> 16) & 1u);
    return r & 0xffff0000u;
}
// pack bf16(x) into low 16, bf16(y) into high 16
__device__ __forceinline__ unsigned pk2_rne(float x, float y) {
    return (bf16rne(x) >> 16) | bf16rne(y);
}
__device__ __forceinline__ float lo16f(unsigned u) { return __uint_as_float(u << 16); }
__device__ __forceinline__ float hi16f(unsigned u) { return __uint_as_float(u & 0xffff0000u); }

// async global->LDS, 16B per lane (dest must be linear: base + lane*16)
__device__ __forceinline__ void gl_lds16(const void* g, void* l) {
    __builtin_amdgcn_global_load_lds((__attribute__((address_space(1))) const void*)g,
                                     (__attribute__((address_space(3))) void*)l, 16, 0, 0);
}

// ---------------------------------------------------------------------------
// Pre-pass 1: split X (f32 [M][K]) -> Xh, Xl (bf16 [M][K]). 8 elems/thread.
// ---------------------------------------------------------------------------
__global__ __launch_bounds__(256) void split_x_kernel(const float* __restrict__ X,
                                                      unsigned short* __restrict__ Xh,
                                                      unsigned short* __restrict__ Xl) {
    size_t i = ((size_t)blockIdx.x * 256 + threadIdx.x) * 8;
    float4 a = *(const float4*)(X + i);
    float4 b = *(const float4*)(X + i + 4);
    unsigned h0 = pk2_rne(a.x, a.y), h1 = pk2_rne(a.z, a.w);
    unsigned h2 = pk2_rne(b.x, b.y), h3 = pk2_rne(b.z, b.w);
    unsigned l0 = pk2_rne(a.x - lo16f(h0), a.y - hi16f(h0));
    unsigned l1 = pk2_rne(a.z - lo16f(h1), a.w - hi16f(h1));
    unsigned l2 = pk2_rne(b.x - lo16f(h2), b.y - hi16f(h2));
    unsigned l3 = pk2_rne(b.z - lo16f(h3), b.w - hi16f(h3));
    uint4 hv; hv.x = h0; hv.y = h1; hv.z = h2; hv.w = h3;
    uint4 lv; lv.x = l0; lv.y = l1; lv.z = l2; lv.w = l3;
    *(uint4*)(Xh + i) = hv;
    *(uint4*)(Xl + i) = lv;
}

// ---------------------------------------------------------------------------
// Pre-pass 2: split + transpose W (f32 [K][N]) -> WhT, WlT (bf16 [N][K]).
// 64x64 tiles via LDS (stride-65 pad: all accesses <=2-way).
// ---------------------------------------------------------------------------
__global__ __launch_bounds__(256) void split_wT_kernel(const float* __restrict__ W,
                                                       unsigned short* __restrict__ WhT,
                                                       unsigned short* __restrict__ WlT) {
    __shared__ float s[64][65];
    const int t  = threadIdx.x;
    const int k0 = blockIdx.x * 64;   // 48 tiles along K
    const int n0 = blockIdx.y * 64;   // 256 tiles along N
    const int c4 = t & 15, r = t >> 4;

#pragma unroll
    for (int p = 0; p < 4; ++p) {
        int rr = r + p * 16;          // k-local row
        float4 v = *(const float4*)(W + (size_t)(k0 + rr) * N_DIM + n0 + c4 * 4);
        s[rr][c4 * 4 + 0] = v.x;
        s[rr][c4 * 4 + 1] = v.y;
        s[rr][c4 * 4 + 2] = v.z;
        s[rr][c4 * 4 + 3] = v.w;
    }
    __syncthreads();
#pragma unroll
    for (int p = 0; p < 4; ++p) {
        int rr = r + p * 16;          // n-local row of the transposed output
        float v0 = s[c4 * 4 + 0][rr];
        float v1 = s[c4 * 4 + 1][rr];
        float v2 = s[c4 * 4 + 2][rr];
        float v3 = s[c4 * 4 + 3][rr];
        unsigned h01 = pk2_rne(v0, v1), h23 = pk2_rne(v2, v3);
        unsigned l01 = pk2_rne(v0 - lo16f(h01), v1 - hi16f(h01));
        unsigned l23 = pk2_rne(v2 - lo16f(h23), v3 - hi16f(h23));
        size_t o = (size_t)(n0 + rr) * K_DIM + k0 + c4 * 4;
        uint2 hv; hv.x = h01; hv.y = h23;
        uint2 lv; lv.x = l01; lv.y = l23;
        *(uint2*)(WhT + o) = hv;
        *(uint2*)(WlT + o) = lv;
    }
}

// ---------------------------------------------------------------------------
// Encoder GEMM, 8-phase counted-vmcnt template (T2+T3+T4+T5) on pre-split
// bf16 planes. BM=BN=256, BK=32, 512 threads = 8 waves (2x4, 128x64 each).
// LDS: double-buffered pair-tiles [256 rows][Ah(32)|Al(32)] bf16, 128 B rows,
// 3-bit slot swizzle s = c ^ (row&7) (both-sides: pre-swizzled gload source,
// XOR'd ds_read). 4 phases / K-tile, 24 MFMA each, vmcnt(2) once per tile.
// Accumulation order identical to previous kernel -> bit-identical output.
// ---------------------------------------------------------------------------
#define BK 32
#define NT (K_DIM / BK)   // 96

__global__ __launch_bounds__(512) void enc_gemm_8ph(
        const unsigned short* __restrict__ Xh, const unsigned short* __restrict__ Xl,
        const unsigned short* __restrict__ WhT, const unsigned short* __restrict__ WlT,
        const float* __restrict__ benc, float* __restrict__ pre) {
    __shared__ unsigned short Ap[2][256 * 64];   // 64 KB (pair tile, dbuf)
    __shared__ unsigned short Bp[2][256 * 64];   // 64 KB

    const int t = threadIdx.x;
    const int b = blockIdx.x;
    // bijective chunked XCD swizzle (512 wgs, 512%8==0); mt fast-varying so
    // same-XCD blocks share the B panel in that XCD's L2.
    const int wg = (b & 7) * 64 + (b >> 3);
    const int mt = wg & 7, nt = wg >> 3;
    const int m0 = mt * 256, n0 = nt * 256;

    // ---- staging precompute: 8 16B-slots per thread (slot id g = j*512+t).
    // g<2048 -> A pair-tile, else B. row=(g>>3)&255, lds slot s=g&7 holds
    // global chunk c = s ^ (row&7); chunks 0-3 = H plane, 4-7 = L plane.
    const unsigned short* srcP[8];
    unsigned short* dstP[8];
#pragma unroll
    for (int j = 0; j < 8; ++j) {
        int g = j * 512 + t;
        int r = (g >> 3) & 255;
        int s = g & 7;
        int c = s ^ (r & 7);
        if (j < 4) {
            const unsigned short* base = (c & 4) ? Xl : Xh;
            srcP[j] = base + (size_t)(m0 + r) * K_DIM + (c & 3) * 8;
            dstP[j] = &Ap[0][(g & 2047) * 8];
        } else {
            const unsigned short* base = (c & 4) ? WlT : WhT;
            srcP[j] = base + (size_t)(n0 + r) * K_DIM + (c & 3) * 8;
            dstP[j] = &Bp[0][(g & 2047) * 8];
        }
    }

    f32x4 acc[8][4];
#pragma unroll
    for (int mi = 0; mi < 8; ++mi)
#pragma unroll
        for (int ni = 0; ni < 4; ++ni) acc[mi][ni] = (f32x4)0.f;

    const int w = t >> 6, lane = t & 63;
    const int wr = w >> 2, wc = w & 3;           // 2 x 4 wave grid
    const int fm = lane & 15, fk = lane >> 4;

    // prologue: stage K-tile 0 into buffer 0
#pragma unroll
    for (int j = 0; j < 8; ++j) gl_lds16(srcP[j], dstP[j]);

// One phase: read A-frags for mi = 2P,2P+1 (swizzled), 24 MFMA, barrier.
#define APHASE(P)                                                                   \
    {                                                                               \
        _Pragma("unroll")                                                           \
        for (int q = 0; q < 2; ++q) {                                               \
            int r = wr * 128 + (2 * (P) + q) * 16 + fm;                             \
            int off = r * 64 + (fk ^ (r & 7)) * 8;                                  \
            aHf[q] = *(const bf16x8*)&Ap[cur][off];                                 \
            aLf[q] = *(const bf16x8*)&Ap[cur][off ^ 32];                            \
        }                                                                           \
        __builtin_amdgcn_s_setprio(1);                                              \
        _Pragma("unroll")                                                           \
        for (int q = 0; q < 2; ++q) {                                               \
            _Pragma("unroll")                                                       \
            for (int ni = 0; ni < 4; ++ni) {                                        \
                acc[2*(P)+q][ni] = __builtin_amdgcn_mfma_f32_16x16x32_bf16(aHf[q], bHf[ni], acc[2*(P)+q][ni], 0, 0, 0); \
                acc[2*(P)+q][ni] = __builtin_amdgcn_mfma_f32_16x16x32_bf16(aHf[q], bLf[ni], acc[2*(P)+q][ni], 0, 0, 0); \
                acc[2*(P)+q][ni] = __builtin_amdgcn_mfma_f32_16x16x32_bf16(aLf[q], bHf[ni], acc[2*(P)+q][ni], 0, 0, 0); \
            }                                                                       \
        }                                                                           \
        __builtin_amdgcn_s_setprio(0);                                              \
        asm volatile("s_barrier" ::: "memory");                                     \
    }

    int cur = 0;
    for (int kt = 0; kt < NT; ++kt) {
        const int kOff = (kt + 1) * BK;        // ushort col offset of NEXT tile
        const int nb = cur ^ 1;
        const int nbO = nb * (256 * 64);       // ushort offset of next buffer
        const bool notLast = (kt + 1 < NT);

        bf16x8 bHf[4], bLf[4], aHf[2], aLf[2];

        // ---- phase 0: stage slots 0,1; counted vmcnt; B-frags; MFMA mi 0,1
        if (notLast) {
            gl_lds16(srcP[0] + kOff, dstP[0] + nbO);
            gl_lds16(srcP[1] + kOff, dstP[1] + nbO);
            asm volatile("s_waitcnt vmcnt(2)\n\ts_barrier" ::: "memory");
        } else {
            asm volatile("s_waitcnt vmcnt(0)\n\ts_barrier" ::: "memory");
        }
#pragma unroll
        for (int ni = 0; ni < 4; ++ni) {
            int r = wc * 64 + ni * 16 + fm;
            int off = r * 64 + (fk ^ (r & 7)) * 8;
            bHf[ni] = *(const bf16x8*)&Bp[cur][off];
            bLf[ni] = *(const bf16x8*)&Bp[cur][off ^ 32];
        }
        APHASE(0)

        // ---- phase 1: stage slots 2,3; MFMA mi 2,3
        if (notLast) {
            gl_lds16(srcP[2] + kOff, dstP[2] + nbO);
            gl_lds16(srcP[3] + kOff, dstP[3] + nbO);
        }
        APHASE(1)

        // ---- phase 2: stage slots 4,5; MFMA mi 4,5
        if (notLast) {
            gl_lds16(srcP[4] + kOff, dstP[4] + nbO);
            gl_lds16(srcP[5] + kOff, dstP[5] + nbO);
        }
        APHASE(2)

        // ---- phase 3: stage slots 6,7; MFMA mi 6,7
        if (notLast) {
            gl_lds16(srcP[6] + kOff, dstP[6] + nbO);
            gl_lds16(srcP[7] + kOff, dstP[7] + nbO);
        }
        APHASE(3)

        cur = nb;
    }
#undef APHASE

    // Epilogue: + b_enc, store (C/D layout: col=lane&15, row=(lane>>4)*4+reg)
#pragma unroll
    for (int ni = 0; ni < 4; ++ni) {
        int col = n0 + wc * 64 + ni * 16 + fm;
        float bv = benc[col];
#pragma unroll
        for (int mi = 0; mi < 8; ++mi) {
            int row = m0 + wr * 128 + mi * 16 + fk * 4;
            float* p = pre + (size_t)row * N_DIM + col;
#pragma unroll
            for (int r = 0; r < 4; ++r) p[(size_t)r * N_DIM] = acc[mi][ni][r] + bv;
        }
    }
}

// ---------------------------------------------------------------------------
// Fallback encoder GEMM (f32 inputs, in-loop split) — used if ws too small.
// ---------------------------------------------------------------------------
__global__ __launch_bounds__(256) void enc_gemm_mfma(const float* __restrict__ X,
                                                     const float* __restrict__ W,
                                                     const float* __restrict__ benc,
                                                     float* __restrict__ pre) {
    __shared__ unsigned short Ahi[128 * LDSTRIDE], Alo[128 * LDSTRIDE];
    __shared__ unsigned short Bhi[128 * LDSTRIDE], Blo[128 * LDSTRIDE];

    const int t   = threadIdx.x;
    const int bid = blockIdx.x;
    const int mt  = bid & 15;
    const int nt  = bid >> 4;
    const int m0  = mt * 128, n0 = nt * 128;

    int am[4], akq[4], bn[4], bkq[4];
    const float* Xp[4];
    const float* Wp[4];
#pragma unroll
    for (int i = 0; i < 4; ++i) {
        int id = t + 256 * i;
        am[i]  = id >> 3;
        akq[i] = id & 7;
        Xp[i]  = X + (size_t)(m0 + am[i]) * K_DIM + akq[i] * 4;
        bn[i]  = id & 127;
        bkq[i] = id >> 7;
        Wp[i]  = W + (size_t)(bkq[i] * 4) * N_DIM + n0 + bn[i];
    }

    f32x4 acc[4][4];
#pragma unroll
    for (int mi = 0; mi < 4; ++mi)
#pragma unroll
        for (int ni = 0; ni < 4; ++ni) acc[mi][ni] = (f32x4)0.f;

    float4 aR[4];
    float  bR[4][4];
#pragma unroll
    for (int i = 0; i < 4; ++i) {
        aR[i] = *(const float4*)(Xp[i]);
#pragma unroll
        for (int j = 0; j < 4; ++j) bR[i][j] = Wp[i][(size_t)j * N_DIM];
    }

    const int w = t >> 6, lane = t & 63;
    const int wm = (w >> 1) * 64, wn = (w & 1) * 64;
    const int fm = lane & 15, fk = lane >> 4;

    for (int k0 = 0; k0 < K_DIM; k0 += 32) {
        __syncthreads();
#pragma unroll
        for (int i = 0; i < 4; ++i) {
            float4 v = aR[i];
            unsigned h0 = pk2_rne(v.x, v.y), h1 = pk2_rne(v.z, v.w);
            unsigned l0 = pk2_rne(v.x - lo16f(h0), v.y - hi16f(h0));
            unsigned l1 = pk2_rne(v.z - lo16f(h1), v.w - hi16f(h1));
            int off = am[i] * LDSTRIDE + akq[i] * 4;
            uint2 uh; uh.x = h0; uh.y = h1;
            uint2 ul; ul.x = l0; ul.y = l1;
            *(uint2*)&Ahi[off] = uh;
            *(uint2*)&Alo[off] = ul;

            float w0 = bR[i][0], w1 = bR[i][1], w2 = bR[i][2], w3 = bR[i][3];
            unsigned g0 = pk2_rne(w0, w1), g1 = pk2_rne(w2, w3);
            unsigned m0u = pk2_rne(w0 - lo16f(g0), w1 - hi16f(g0));
            unsigned m1u = pk2_rne(w2 - lo16f(g1), w3 - hi16f(g1));
            int boff = bn[i] * LDSTRIDE + bkq[i] * 4;
            uint2 gh; gh.x = g0; gh.y = g1;
            uint2 gl; gl.x = m0u; gl.y = m1u;
            *(uint2*)&Bhi[boff] = gh;
            *(uint2*)&Blo[boff] = gl;
        }
        __syncthreads();

        if (k0 + 32 < K_DIM) {
#pragma unroll
            for (int i = 0; i < 4; ++i) {
                aR[i] = *(const float4*)(Xp[i] + (k0 + 32));
                const float* p = Wp[i] + (size_t)(k0 + 32) * N_DIM;
#pragma unroll
                for (int j = 0; j < 4; ++j) bR[i][j] = p[(size_t)j * N_DIM];
            }
        }

        bf16x8 aH[4], aL[4];
#pragma unroll
        for (int mi = 0; mi < 4; ++mi) {
            int r = (wm + mi * 16 + fm) * LDSTRIDE + fk * 8;
            aH[mi] = *(const bf16x8*)&Ahi[r];
            aL[mi] = *(const bf16x8*)&Alo[r];
        }
#pragma unroll
        for (int ni = 0; ni < 4; ++ni) {
            int r = (wn + ni * 16 + fm) * LDSTRIDE + fk * 8;
            bf16x8 bH = *(const bf16x8*)&Bhi[r];
            bf16x8 bL = *(const bf16x8*)&Blo[r];
#pragma unroll
            for (int mi = 0; mi < 4; ++mi) {
                acc[mi][ni] = __builtin_amdgcn_mfma_f32_16x16x32_bf16(aH[mi], bH, acc[mi][ni], 0, 0, 0);
                acc[mi][ni] = __builtin_amdgcn_mfma_f32_16x16x32_bf16(aH[mi], bL, acc[mi][ni], 0, 0, 0);
                acc[mi][ni] = __builtin_amdgcn_mfma_f32_16x16x32_bf16(aL[mi], bH, acc[mi][ni], 0, 0, 0);
            }
        }
    }

    const int frow = fk * 4, fcol = fm;
#pragma unroll
    for (int ni = 0; ni < 4; ++ni) {
        int col = n0 + wn + ni * 16 + fcol;
        float bv = benc[col];
#pragma unroll
        for (int mi = 0; mi < 4; ++mi) {
            int row = m0 + wm + mi * 16 + frow;
            float* p = pre + (size_t)row * N_DIM + col;
#pragma unroll
            for (int r = 0; r < 4; ++r) p[(size_t)r * N_DIM] = acc[mi][ni][r] + bv;
        }
    }
}

// ---------------------------------------------------------------------------
// Top-k per row (in place). Unchanged.
// ---------------------------------------------------------------------------
__device__ __forceinline__ unsigned sortkey(float f) {
    unsigned u = __float_as_uint(f);
    return (u & 0x80000000u) ? ~u : (u | 0x80000000u);
}

__device__ __forceinline__ int wave_red_int(int v) {
#pragma unroll
    for (int o = 32; o > 0; o >>= 1) v += __shfl_xor(v, o);
    return v;
}

__global__ __launch_bounds__(256) void topk_kernel(float* __restrict__ z,
                                                   int* __restrict__ oIdx,
                                                   float* __restrict__ oVal) {
    __shared__ unsigned short k16[N_DIM];   // 32 KB
    __shared__ int s4[4];
    __shared__ int s_candN;
    __shared__ int s_candIdx[256];
    __shared__ unsigned s_candKey[256];
    __shared__ int s_quota;
    __shared__ int s_outPos;

    const int row = blockIdx.x;
    const int t = threadIdx.x;
    float* zr = z + (size_t)row * N_DIM;

    if (t == 0) { s_candN = 0; s_outPos = 0; }

    for (int i = t; i < N_DIM; i += 256) {
        k16[i] = (unsigned short)(sortkey(zr[i]) >> 16);
    }
    __syncthreads();

    unsigned cur = 0;
    for (int bit = 15; bit >= 0; --bit) {
        unsigned cand = cur | (1u << bit);
        int c = 0;
        for (int i = t; i < N_DIM; i += 256) c += (k16[i] >= cand) ? 1 : 0;
        c = wave_red_int(c);
        __syncthreads();
        if ((t & 63) == 0) s4[t >> 6] = c;
        __syncthreads();
        int total = s4[0] + s4[1] + s4[2] + s4[3];
        if (total >= TOPK) cur = cand;
    }

    {
        int c = 0;
        for (int i = t; i < N_DIM; i += 256) c += (k16[i] > cur) ? 1 : 0;
        c = wave_red_int(c);
        __syncthreads();
        if ((t & 63) == 0) s4[t >> 6] = c;
        __syncthreads();
        int cgt = s4[0] + s4[1] + s4[2] + s4[3];
        if (t == 0) s_quota = TOPK - cgt;
    }
    __syncthreads();

    for (int i = t; i < N_DIM; i += 256) {
        if (k16[i] == (unsigned short)cur) {
            int p = atomicAdd(&s_candN, 1);
            if (p < 256) {
                s_candIdx[p] = i;
                s_candKey[p] = sortkey(zr[i]);
            }
        }
    }
    __syncthreads();

    if (t == 0) {
        int n = s_candN < 256 ? s_candN : 256;
        int q = s_quota;
        if (q > n) q = n;
        s_quota = q;
        for (int a = 0; a < q; ++a) {
            int best = a;
            for (int b = a + 1; b < n; ++b) {
                if (s_candKey[b] > s_candKey[best] ||
                    (s_candKey[b] == s_candKey[best] && s_candIdx[b] < s_candIdx[best]))
                    best = b;
            }
            if (best != a) {
                unsigned tk = s_candKey[a]; s_candKey[a] = s_candKey[best]; s_candKey[best] = tk;
                int ti = s_candIdx[a]; s_candIdx[a] = s_candIdx[best]; s_candIdx[best] = ti;
            }
        }
    }
    __syncthreads();

    const int quota = s_quota;
    for (int i = t; i < N_DIM; i += 256) {
        float f = zr[i];
        unsigned short kk = k16[i];
        bool sel = kk > (unsigned short)cur;
        if (!sel && kk == (unsigned short)cur) {
            for (int j = 0; j < quota; ++j)
                if (s_candIdx[j] == i) { sel = true; break; }
        }
        float zv = sel ? fmaxf(f, 0.f) : 0.f;
        zr[i] = zv;
        if (sel) {
            int p = atomicAdd(&s_outPos, 1);
            oIdx[row * TOPK + p] = i;
            oVal[row * TOPK + p] = zv;
        }
    }
}

// ---------------------------------------------------------------------------
// Sparse decode + fused loss. Unchanged.
// ---------------------------------------------------------------------------
__global__ __launch_bounds__(256) void decode_kernel(const int* __restrict__ idxL,
                                                     const float* __restrict__ valL,
                                                     const float* __restrict__ Wdec,
                                                     const float* __restrict__ bdec,
                                                     const float* __restrict__ x,
                                                     float* __restrict__ xhat,
                                                     float* __restrict__ loss) {
    __shared__ int s_idx[TOPK];
    __shared__ float s_val[TOPK];
    __shared__ float sred[4];

    const int row = blockIdx.x;
    const int t = threadIdx.x;

    if (t < TOPK) {
        s_idx[t] = idxL[row * TOPK + t];
        s_val[t] = valL[row * TOPK + t];
    }
    __syncthreads();

    float acc[12];
#pragma unroll
    for (int e = 0; e < 12; ++e) acc[e] = bdec[t + e * 256];

    for (int i = 0; i < TOPK; ++i) {
        const float v = s_val[i];
        const float* wr = Wdec + (size_t)s_idx[i] * K_DIM;
#pragma unroll
        for (int e = 0; e < 12; ++e)
            acc[e] = fmaf(v, wr[t + e * 256], acc[e]);
    }

    const float* xr = x + (size_t)row * K_DIM;
    float* xo = xhat + (size_t)row * K_DIM;
    float part = 0.f;
#pragma unroll
    for (int e = 0; e < 12; ++e) {
        float d = acc[e] - xr[t + e * 256];
        part = fmaf(d, d, part);
        xo[t + e * 256] = acc[e];
    }

#pragma unroll
    for (int o = 32; o > 0; o >>= 1) part += __shfl_xor(part, o);
    if ((t & 63) == 0) sred[t >> 6] = part;
    __syncthreads();
    if (t == 0) {
        float total = sred[0] + sred[1] + sred[2] + sred[3];
        atomicAdd(loss, total * (1.0f / 8192.0f));
    }
}

// ---------------------------------------------------------------------------
extern "C" void kernel_launch(void* const* d_in, const int* in_sizes, int n_in,
                              void* d_out, int out_size, void* d_ws, size_t ws_size,
                              hipStream_t stream) {
    const float* x     = (const float*)d_in[0];
    const float* W_enc = (const float*)d_in[1];
    const float* b_enc = (const float*)d_in[2];
    const float* W_dec = (const float*)d_in[3];
    const float* b_dec = (const float*)d_in[4];

    float* out  = (float*)d_out;
    float* loss = out;
    float* xhat = out + 1;
    float* z    = out + 1 + XHAT_ELEMS;   // z section doubles as `pre` scratch

    const size_t idxB   = (size_t)B_ROWS * TOPK * sizeof(int);   // 1 MB
    const size_t planeW = (size_t)K_DIM * N_DIM * 2;             // 100.7 MB
    const size_t planeX = (size_t)B_ROWS * K_DIM * 2;            // 12.6 MB
    const size_t need   = 2 * idxB + 2 * planeW + 2 * planeX;    // ~228.6 MB

    int*   oIdx = (int*)d_ws;
    float* oVal = (float*)((char*)d_ws + idxB);

    (void)hipMemsetAsync(loss, 0, sizeof(float), stream);

    if (ws_size >= need) {
        unsigned short* WhT = (unsigned short*)((char*)d_ws + 2 * idxB);
        unsigned short* WlT = (unsigned short*)((char*)WhT + planeW);
        unsigned short* Xh  = (unsigned short*)((char*)WlT + planeW);
        unsigned short* Xl  = (unsigned short*)((char*)Xh + planeX);

        split_x_kernel<<<(B_ROWS * K_DIM) / (8 * 256), 256, 0, stream>>>(x, Xh, Xl);
        split_wT_kernel<<<dim3(K_DIM / 64, N_DIM / 64), 256, 0, stream>>>(W_enc, WhT, WlT);
        enc_gemm_8ph<<<512, 512, 0, stream>>>(Xh, Xl, WhT, WlT, b_enc, z);
    } else {
        enc_gemm_mfma<<<2048, 256, 0, stream>>>(x, W_enc, b_enc, z);
    }

    topk_kernel<<<B_ROWS, 256, 0, stream>>>(z, oIdx, oVal);

    decode_kernel<<<B_ROWS, 256, 0, stream>>>(oIdx, oVal, W_dec, b_dec, x, xhat, loss);
}